// Round 2
// 398.115 us; speedup vs baseline: 1.1561x; 1.1561x over previous
//
#include <hip/hip_runtime.h>

// 2-layer LSTM (B=4096,T=512,D=16,H=50)+FC via single-wave MFMA.
// R8: R6 + (kept from R7) MFMA-chained accumulators, x-register prefetch,
// 4x unroll with literal ring-slot/parity offsets, pair-fused cell.
// Reverted from R7: 16x16x16 x-projection (unverified fragment layout) and
// shared-rcp on the recurrent c-path (conditioning). cell2 now uses separate
// rcp per cell for c (R6-equivalent), shared rcp only for h (error << fp16
// quant), with exp2 clamp 40 (tanh saturates in f32 at ~36) so the shared
// product can never overflow.

#define TSTEPS 512
#define DIN 16
#define HID 50
#define BPB 16

typedef _Float16 half8 __attribute__((ext_vector_type(8)));
typedef _Float16 half4v __attribute__((ext_vector_type(4)));
typedef float f32x4 __attribute__((ext_vector_type(4)));

#define MF(A, B, C) __builtin_amdgcn_mfma_f32_16x16x32_f16((A), (B), (C), 0, 0, 0)

// LDS: h double-buffered [2][16][144]; x 4-slot ring [4][16][80].
#define HBUF 2304
#define XBUF 1280
#define H0_O 0
#define H1_O 4608
#define X_O  9216
#define SH_BYTES (9216 + 4 * XBUF)   // 14336

// Barrier WITHOUT vmcnt drain: LDS ordering only (wave7 global loads stay in flight).
#define BAR() asm volatile("s_waitcnt lgkmcnt(0)\ns_barrier" ::: "memory")

__device__ __forceinline__ unsigned pack2h(float a, float b) {
  union { _Float16 h[2]; unsigned u; } pk;
  pk.h[0] = (_Float16)a;
  pk.h[1] = (_Float16)b;
  return pk.u;
}

// Pair-fused LSTM cell (two independent cells A,B): 10 exp2 + 3 rcp
// (vs 10 exp2 + 6 rcp for two R6 cells). Gate order i,f,g,o.
//   c' = [(eg-1)*F + c*A*Bg] / (F*A*Bg)   with A=1+e^-i, F=1+e^-f, Bg=1+e^2g
//      = sigmoid(i)*tanh(g) + sigmoid(f)*c        (separate rcp per cell)
//   h  = (ec-1)/((1+eo)(1+ec)), ec=e^2c           (rcp SHARED across the pair;
//        qA*qB <= (2*(1+2^40))^2 ~ 4.8e24, no overflow; err ~1e-6 << fp16)
__device__ __forceinline__ void cell2(const f32x4 gA, const f32x4 gB,
                                      float& cA, float& cB, float& hA, float& hB) {
  const float L2E = 1.4426950408889634f;
  float eiA = __builtin_amdgcn_exp2f(-L2E * gA[0]);
  float efA = __builtin_amdgcn_exp2f(-L2E * gA[1]);
  float egA = __builtin_amdgcn_exp2f(fminf(2.f * L2E * gA[2], 40.f));
  float eoA = __builtin_amdgcn_exp2f(-L2E * gA[3]);
  float eiB = __builtin_amdgcn_exp2f(-L2E * gB[0]);
  float efB = __builtin_amdgcn_exp2f(-L2E * gB[1]);
  float egB = __builtin_amdgcn_exp2f(fminf(2.f * L2E * gB[2], 40.f));
  float eoB = __builtin_amdgcn_exp2f(-L2E * gB[3]);
  float aA = 1.f + eiA, fA = 1.f + efA, bA = 1.f + egA;
  float aB = 1.f + eiB, fB = 1.f + efB, bB = 1.f + egB;
  float abA = aA * bA, abB = aB * bB;
  float tA = fmaf(egA - 1.f, fA, cA * abA);
  float tB = fmaf(egB - 1.f, fB, cB * abB);
  cA = tA * __builtin_amdgcn_rcpf(fA * abA);
  cB = tB * __builtin_amdgcn_rcpf(fB * abB);
  float ecA = __builtin_amdgcn_exp2f(fminf(2.f * L2E * cA, 40.f));
  float ecB = __builtin_amdgcn_exp2f(fminf(2.f * L2E * cB, 40.f));
  float qA = (1.f + eoA) * (1.f + ecA);
  float qB = (1.f + eoB) * (1.f + ecB);
  float r2 = __builtin_amdgcn_rcpf(qA * qB);
  hA = (ecA - 1.f) * (r2 * qB);
  hB = (ecB - 1.f) * (r2 * qA);
}

// A-frag (fp16, 16x16x32): lane row g'=16gt+(lane&15)=4u+j, k-pos p=kt*32+(lane>>4)*8+i.
// permk: pos p holds source k = 8*(p>>3) + 4*(p&1) + ((p>>1)&3).
__device__ __forceinline__ half8 load_wfrag(const float* __restrict__ W, int kld,
                                            bool permk, int kreal, int gt, int kt,
                                            int lane) {
  const int gp = 16 * gt + (lane & 15);
  const int u = gp >> 2, j = gp & 3;
  const int kb = kt * 32 + (lane >> 4) * 8;
  half8 f;
#pragma unroll
  for (int i = 0; i < 8; ++i) {
    const int p = kb + i;
    const int kk = permk ? ((p & ~7) + (((p & 1) << 2) | ((p >> 1) & 3))) : p;
    float v = (u < HID && kk < kreal) ? W[(j * HID + u) * kld + kk] : 0.f;
    f[i] = (_Float16)v;
  }
  return f;
}

extern "C" __global__ void __launch_bounds__(512, 2)
lstm2_v8(const float* __restrict__ x,
         const float* __restrict__ Wih0, const float* __restrict__ Whh0,
         const float* __restrict__ bih0, const float* __restrict__ bhh0,
         const float* __restrict__ Wih1, const float* __restrict__ Whh1,
         const float* __restrict__ bih1, const float* __restrict__ bhh1,
         const float* __restrict__ Wfc, const float* __restrict__ bfc,
         float* __restrict__ out) {
  __shared__ __align__(16) char sh[SH_BYTES];
  const int tid = threadIdx.x;
  const int lane = tid & 63;
  const int wv = tid >> 6;
  const int bcol = lane & 15;
  const int kg = lane >> 4;
  const int bbase = blockIdx.x * BPB;
  const bool comp = (wv < 7);

  // x-staging mapping (wave 7): lane -> (batch row sbb, float-quad q)
  const int sbb = lane >> 2, q = lane & 3;
  const float* xrow = x + ((size_t)(bbase + sbb) * TSTEPS) * DIN + q * 4;

  for (int i = tid; i < SH_BYTES / 4; i += 512) ((int*)sh)[i] = 0;

  // ---- register-resident fp16 weight fragments + f32 bias ----
  half8 w0x[2], w0h[2][2], w1i[2][2], w1h[2][2];
  f32x4 bias0v[2] = {{0,0,0,0},{0,0,0,0}}, bias1v[2] = {{0,0,0,0},{0,0,0,0}};
  if (comp) {
#pragma unroll
    for (int gi = 0; gi < 2; ++gi) {
      const int gt = 2 * wv + gi;
      w0x[gi] = load_wfrag(Wih0, DIN, false, DIN, gt, 0, lane);
#pragma unroll
      for (int kt = 0; kt < 2; ++kt) {
        w0h[gi][kt] = load_wfrag(Whh0, HID, true, HID, gt, kt, lane);
        w1i[gi][kt] = load_wfrag(Wih1, HID, true, HID, gt, kt, lane);
        w1h[gi][kt] = load_wfrag(Whh1, HID, true, HID, gt, kt, lane);
      }
      const int u = 8 * wv + 4 * gi + kg;
      if (u < HID) {
#pragma unroll
        for (int j = 0; j < 4; ++j) {
          bias0v[gi][j] = bih0[j * HID + u] + bhh0[j * HID + u];
          bias1v[gi][j] = bih1[j * HID + u] + bhh1[j * HID + u];
        }
      }
    }
  }
  float c0[2] = {0.f, 0.f}, c1[2] = {0.f, 0.f};
  const int hoff = bcol * 144 + kg * 16;
  const int xoff = bcol * 80 + kg * 16;
  const int wo32 = bcol * 144 + wv * 16 + kg * 4;

  BAR();  // LDS zeroed

  // stage x[0..2] -> slots 0..2 (wave 7, direct)
  if (wv == 7) {
#pragma unroll
    for (int t = 0; t < 3; ++t) {
      float4 xq = *(const float4*)(xrow + (size_t)t * DIN);
      half4v h4;
#pragma unroll
      for (int i = 0; i < 4; ++i) h4[i] = (_Float16)((const float*)&xq)[i];
      *(half4v*)(sh + X_O + t * XBUF + sbb * 80 + q * 8) = h4;
    }
  }
  BAR();

  // prologue step: h0[0] = cell(bias0 + Wih0 x[0]) -> h0 buf 0; prefetch x[1] to reg.
  float4 xrA, xrB;
  half8 bxc;
  if (comp) {
    half8 bx0 = *(const half8*)(sh + X_O + 0 * XBUF + xoff);
    bxc = *(const half8*)(sh + X_O + 1 * XBUF + xoff);
    f32x4 a0 = MF(w0x[0], bx0, bias0v[0]);
    f32x4 a1 = MF(w0x[1], bx0, bias0v[1]);
    float h0a, h0b;
    cell2(a0, a1, c0[0], c0[1], h0a, h0b);
    *(unsigned*)(sh + H0_O + wo32) = pack2h(h0a, h0b);
  } else if (wv == 7) {  // issue the register ring: x[3], x[4]
    xrA = *(const float4*)(xrow + (size_t)3 * DIN);
    xrB = *(const float4*)(xrow + (size_t)4 * DIN);
  }
  BAR();

// one compute step at compile-time h-parity P (reads h bufs P, writes P^1),
// using register x-frag bxc (= x[t+1]), prefetching next phase's x from ring
// slot XSN. MFMA chained into the accumulator; cell pair fused.
#define STEPCOMP(P, XSN)                                                       \
  do {                                                                         \
    half8 bh0[2], bh1[2];                                                      \
    _Pragma("unroll") for (int kt = 0; kt < 2; ++kt) {                         \
      bh0[kt] = *(const half8*)(sh + H0_O + (P)*HBUF + hoff + kt * 64);        \
      bh1[kt] = *(const half8*)(sh + H1_O + (P)*HBUF + hoff + kt * 64);        \
    }                                                                          \
    half8 bxn = *(const half8*)(sh + X_O + (XSN)*XBUF + xoff);                 \
    float h1n[2], h0n[2];                                                      \
    _Pragma("unroll") for (int gi = 0; gi < 2; ++gi) {                         \
      f32x4 qv = MF(w1i[gi][0], bh0[0], bias1v[gi]);                           \
      qv = MF(w1h[gi][0], bh1[0], qv);                                         \
      qv = MF(w1i[gi][1], bh0[1], qv);                                         \
      qv = MF(w1h[gi][1], bh1[1], qv);                                         \
      f32x4 rv = MF(w0x[gi], bxc, bias0v[gi]);                                 \
      rv = MF(w0h[gi][0], bh0[0], rv);                                         \
      rv = MF(w0h[gi][1], bh0[1], rv);                                         \
      cell2(qv, rv, c1[gi], c0[gi], h1n[gi], h0n[gi]);                         \
    }                                                                          \
    *(unsigned*)(sh + H1_O + ((P) ^ 1) * HBUF + wo32) = pack2h(h1n[0], h1n[1]);\
    *(unsigned*)(sh + H0_O + ((P) ^ 1) * HBUF + wo32) = pack2h(h0n[0], h0n[1]);\
    bxc = bxn;                                                                 \
  } while (0)

// wave 7: ds-write XR (holds x[t+3]) into literal SLOT=(t+3)&3, load x[t+5].
#define STEPX(T, SLOT, XR)                                                     \
  do {                                                                         \
    half4v h4;                                                                 \
    _Pragma("unroll") for (int i = 0; i < 4; ++i)                              \
        h4[i] = (_Float16)((const float*)&(XR))[i];                            \
    *(half4v*)(sh + X_O + (SLOT)*XBUF + sbb * 80 + q * 8) = h4;                \
    int tl = (T) + 5;                                                          \
    if (tl > TSTEPS - 1) tl = TSTEPS - 1;                                      \
    (XR) = *(const float4*)(xrow + (size_t)tl * DIN);                          \
  } while (0)

  for (int s = 0; s < TSTEPS; s += 4) {
    // phase s   (P=0): uses x[s+1] (bxc), prefetch slot 2 = x[s+2]
    if (comp) { STEPCOMP(0, 2); } else if (wv == 7) { STEPX(s, 3, xrA); }
    BAR();
    // phase s+1 (P=1): uses x[s+2], prefetch slot 3 = x[s+3]
    if (comp) { STEPCOMP(1, 3); } else if (wv == 7) { STEPX(s + 1, 0, xrB); }
    BAR();
    // phase s+2 (P=0): uses x[s+3], prefetch slot 0 = x[s+4]
    if (comp) { STEPCOMP(0, 0); } else if (wv == 7) { STEPX(s + 2, 1, xrA); }
    BAR();
    // phase s+3 (P=1): uses x[s+4], prefetch slot 1 = x[s+5]
    if (comp) { STEPCOMP(1, 1); } else if (wv == 7) { STEPX(s + 3, 2, xrB); }
    BAR();
  }

  // ---- FC epilogue: h1[511] in buf 0; read through pi-permutation ----
  if (tid < BPB) {
    float acc = bfc[0];
#pragma unroll 10
    for (int u = 0; u < HID; ++u) {
      const int pp = (u & ~7) + 2 * (u & 3) + ((u >> 2) & 1);
      float h = (float)(*(const _Float16*)(sh + H1_O + tid * 144 + pp * 2));
      acc = fmaf(Wfc[u], h, acc);
    }
    out[bbase + tid] = acc;
  }
}

extern "C" void kernel_launch(void* const* d_in, const int* in_sizes, int n_in,
                              void* d_out, int out_size, void* d_ws, size_t ws_size,
                              hipStream_t stream) {
  (void)in_sizes; (void)n_in; (void)d_ws; (void)ws_size; (void)out_size;
  lstm2_v8<<<dim3(4096 / BPB), dim3(512), 0, stream>>>(
      (const float*)d_in[0], (const float*)d_in[1], (const float*)d_in[2],
      (const float*)d_in[3], (const float*)d_in[4], (const float*)d_in[5],
      (const float*)d_in[6], (const float*)d_in[7], (const float*)d_in[8],
      (const float*)d_in[9], (const float*)d_in[10], (float*)d_out);
}

// Round 4
// 330.681 us; speedup vs baseline: 1.3919x; 1.2039x over previous
//
#include <hip/hip_runtime.h>

// 2-layer LSTM (B=4096,T=512,D=16,H=50)+FC via single-wave MFMA.
// R10 = R9 with the cvt_pkrtz return-type fix (__fp16 vector, not _Float16).
// R9: R8 + (1) pre-scaled weights/biases (gates arrive in exp2-domain:
// i,f,o rows scaled by -log2e, g rows by +2log2e; cell state kept scaled
// C=2log2e*c) -- kills 8 v_mul per cell-pair; (2) f32x2-packed cell math
// (targets v_pk_{add,mul,fma}_f32, VOP3P) with layer-paired cells;
// (3) clamps moved to eo/ec@30 (overflow-proof pair products <=2^122),
// eg clamp dropped (bounded <=2^57, products <=2^114); (4) h-store via
// v_cvt_pkrtz (1 instr). Structure (stager wave, x ring, MFMA chains,
// 4x unroll, barriers) identical to R8.

#define TSTEPS 512
#define DIN 16
#define HID 50
#define BPB 16

typedef _Float16 half8 __attribute__((ext_vector_type(8)));
typedef _Float16 half4v __attribute__((ext_vector_type(4)));
typedef __fp16 fp16x2 __attribute__((ext_vector_type(2)));
typedef float f32x4 __attribute__((ext_vector_type(4)));
typedef float f32x2 __attribute__((ext_vector_type(2)));

#define MF(A, B, C) __builtin_amdgcn_mfma_f32_16x16x32_f16((A), (B), (C), 0, 0, 0)

// LDS: h double-buffered [2][16][144]; x 4-slot ring [4][16][80].
#define HBUF 2304
#define XBUF 1280
#define H0_O 0
#define H1_O 4608
#define X_O  9216
#define SH_BYTES (9216 + 4 * XBUF)   // 14336

// Barrier WITHOUT vmcnt drain: LDS ordering only (wave7 global loads stay in flight).
#define BAR() asm volatile("s_waitcnt lgkmcnt(0)\ns_barrier" ::: "memory")

#define NL2E  (-1.4426950408889634f)   // -log2(e): scale for gates i,f,o
#define P2L2E (2.8853900817779268f)    // +2*log2(e): scale for gate g

__device__ __forceinline__ unsigned pack2h(float a, float b) {
  union { fp16x2 h; unsigned u; } pk;
  pk.h = __builtin_amdgcn_cvt_pkrtz(a, b);
  return pk.u;
}

// Pair-fused LSTM cell on PRE-SCALED gates, f32x2-packed (two independent
// cells per call; pairing is across gi within one layer).
//   g[0]=-L2E*i  g[1]=-L2E*f  g[2]=+2L2E*g  g[3]=-L2E*o   (from scaled MFMA)
//   C = 2L2E*c (scaled cell state).
//   ei=2^g0, ef=2^g1, eg=2^g2, eo=2^min(g3,30)
//   a=1+ei f=1+ef b=1+eg ; ab=a*b ; f2=fma(ef,2L2E,2L2E)=2L2E*f
//   C' = [ (eg-1)*f2 + C*ab ] * rcp(f*ab)        (per-cell rcp: conditioning)
//   ec = 2^min(C',30) ; q=(1+eo)(1+ec) ; h=(ec-1)/q  (rcp shared across pair;
//   q<=2^61 so pair product <=2^122, no overflow)
__device__ __forceinline__ f32x2 cell2p(const f32x4 gA, const f32x4 gB, f32x2& C) {
  f32x2 gi = {gA[0], gB[0]}, gf = {gA[1], gB[1]};
  f32x2 gg = {gA[2], gB[2]}, go = {gA[3], gB[3]};
  f32x2 ei, ef, eg, eo;
  ei[0] = __builtin_amdgcn_exp2f(gi[0]); ei[1] = __builtin_amdgcn_exp2f(gi[1]);
  ef[0] = __builtin_amdgcn_exp2f(gf[0]); ef[1] = __builtin_amdgcn_exp2f(gf[1]);
  eg[0] = __builtin_amdgcn_exp2f(gg[0]); eg[1] = __builtin_amdgcn_exp2f(gg[1]);
  eo[0] = __builtin_amdgcn_exp2f(fminf(go[0], 30.f));
  eo[1] = __builtin_amdgcn_exp2f(fminf(go[1], 30.f));
  const f32x2 one = {1.f, 1.f};
  const f32x2 c2 = {P2L2E, P2L2E};
  f32x2 a = one + ei, f = one + ef, b = one + eg;
  f32x2 ab = a * b;
  f32x2 f2 = ef * c2 + c2;                 // 2L2E * f
  f32x2 t = (eg - one) * f2 + C * ab;
  f32x2 p = f * ab;
  f32x2 rp;
  rp[0] = __builtin_amdgcn_rcpf(p[0]);
  rp[1] = __builtin_amdgcn_rcpf(p[1]);
  C = t * rp;
  f32x2 ec;
  ec[0] = __builtin_amdgcn_exp2f(fminf(C[0], 30.f));
  ec[1] = __builtin_amdgcn_exp2f(fminf(C[1], 30.f));
  f32x2 q = (one + eo) * (one + ec);
  float r2 = __builtin_amdgcn_rcpf(q[0] * q[1]);
  f32x2 h;
  h[0] = (ec[0] - 1.f) * (r2 * q[1]);
  h[1] = (ec[1] - 1.f) * (r2 * q[0]);
  return h;
}

// A-frag (fp16, 16x16x32): lane row g'=16gt+(lane&15)=4u+j, k-pos p=kt*32+(lane>>4)*8+i.
// permk: pos p holds source k = 8*(p>>3) + 4*(p&1) + ((p>>1)&3).
// scale: per-row gate scale (j = lane&3), folded into the fp16 fragment.
__device__ __forceinline__ half8 load_wfrag(const float* __restrict__ W, int kld,
                                            bool permk, int kreal, int gt, int kt,
                                            int lane, float scale) {
  const int gp = 16 * gt + (lane & 15);
  const int u = gp >> 2, j = gp & 3;
  const int kb = kt * 32 + (lane >> 4) * 8;
  half8 f;
#pragma unroll
  for (int i = 0; i < 8; ++i) {
    const int p = kb + i;
    const int kk = permk ? ((p & ~7) + (((p & 1) << 2) | ((p >> 1) & 3))) : p;
    float v = (u < HID && kk < kreal) ? W[(j * HID + u) * kld + kk] : 0.f;
    f[i] = (_Float16)(v * scale);
  }
  return f;
}

extern "C" __global__ void __launch_bounds__(512, 2)
lstm2_v10(const float* __restrict__ x,
          const float* __restrict__ Wih0, const float* __restrict__ Whh0,
          const float* __restrict__ bih0, const float* __restrict__ bhh0,
          const float* __restrict__ Wih1, const float* __restrict__ Whh1,
          const float* __restrict__ bih1, const float* __restrict__ bhh1,
          const float* __restrict__ Wfc, const float* __restrict__ bfc,
          float* __restrict__ out) {
  __shared__ __align__(16) char sh[SH_BYTES];
  const int tid = threadIdx.x;
  const int lane = tid & 63;
  const int wv = tid >> 6;
  const int bcol = lane & 15;
  const int kg = lane >> 4;
  const int bbase = blockIdx.x * BPB;
  const bool comp = (wv < 7);

  // x-staging mapping (wave 7): lane -> (batch row sbb, float-quad q)
  const int sbb = lane >> 2, q = lane & 3;
  const float* xrow = x + ((size_t)(bbase + sbb) * TSTEPS) * DIN + q * 4;

  for (int i = tid; i < SH_BYTES / 4; i += 512) ((int*)sh)[i] = 0;

  // ---- register-resident PRE-SCALED fp16 weight fragments + scaled f32 bias ----
  const float wsc = ((lane & 3) == 2) ? P2L2E : NL2E;  // A-frag row j = lane&3
  half8 w0x[2], w0h[2][2], w1i[2][2], w1h[2][2];
  f32x4 bias0v[2] = {{0,0,0,0},{0,0,0,0}}, bias1v[2] = {{0,0,0,0},{0,0,0,0}};
  if (comp) {
#pragma unroll
    for (int gi = 0; gi < 2; ++gi) {
      const int gt = 2 * wv + gi;
      w0x[gi] = load_wfrag(Wih0, DIN, false, DIN, gt, 0, lane, wsc);
#pragma unroll
      for (int kt = 0; kt < 2; ++kt) {
        w0h[gi][kt] = load_wfrag(Whh0, HID, true, HID, gt, kt, lane, wsc);
        w1i[gi][kt] = load_wfrag(Wih1, HID, true, HID, gt, kt, lane, wsc);
        w1h[gi][kt] = load_wfrag(Whh1, HID, true, HID, gt, kt, lane, wsc);
      }
      const int u = 8 * wv + 4 * gi + kg;
      if (u < HID) {
#pragma unroll
        for (int j = 0; j < 4; ++j) {
          const float bs = (j == 2) ? P2L2E : NL2E;  // acc elem j = gate j
          bias0v[gi][j] = bs * (bih0[j * HID + u] + bhh0[j * HID + u]);
          bias1v[gi][j] = bs * (bih1[j * HID + u] + bhh1[j * HID + u]);
        }
      }
    }
  }
  f32x2 C0 = {0.f, 0.f}, C1 = {0.f, 0.f};  // scaled cell states, paired over gi
  const int hoff = bcol * 144 + kg * 16;
  const int xoff = bcol * 80 + kg * 16;
  const int wo32 = bcol * 144 + wv * 16 + kg * 4;

  BAR();  // LDS zeroed

  // stage x[0..2] -> slots 0..2 (wave 7, direct)
  if (wv == 7) {
#pragma unroll
    for (int t = 0; t < 3; ++t) {
      float4 xq = *(const float4*)(xrow + (size_t)t * DIN);
      half4v h4;
#pragma unroll
      for (int i = 0; i < 4; ++i) h4[i] = (_Float16)((const float*)&xq)[i];
      *(half4v*)(sh + X_O + t * XBUF + sbb * 80 + q * 8) = h4;
    }
  }
  BAR();

  // prologue step: h0[0] = cell(bias0 + Wih0 x[0]) -> h0 buf 0; prefetch x[1] to reg.
  float4 xrA, xrB;
  half8 bxc;
  if (comp) {
    half8 bx0 = *(const half8*)(sh + X_O + 0 * XBUF + xoff);
    bxc = *(const half8*)(sh + X_O + 1 * XBUF + xoff);
    f32x4 a0 = MF(w0x[0], bx0, bias0v[0]);
    f32x4 a1 = MF(w0x[1], bx0, bias0v[1]);
    f32x2 H0 = cell2p(a0, a1, C0);
    *(unsigned*)(sh + H0_O + wo32) = pack2h(H0[0], H0[1]);
  } else if (wv == 7) {  // issue the register ring: x[3], x[4]
    xrA = *(const float4*)(xrow + (size_t)3 * DIN);
    xrB = *(const float4*)(xrow + (size_t)4 * DIN);
  }
  BAR();

// one compute step at compile-time h-parity P (reads h bufs P, writes P^1),
// using register x-frag bxc (= x[t+1]), prefetching next phase's x from ring
// slot XSN. MFMA chained into the accumulator; cells layer-paired in f32x2.
#define STEPCOMP(P, XSN)                                                       \
  do {                                                                         \
    half8 bh0[2], bh1[2];                                                      \
    _Pragma("unroll") for (int kt = 0; kt < 2; ++kt) {                         \
      bh0[kt] = *(const half8*)(sh + H0_O + (P)*HBUF + hoff + kt * 64);        \
      bh1[kt] = *(const half8*)(sh + H1_O + (P)*HBUF + hoff + kt * 64);        \
    }                                                                          \
    half8 bxn = *(const half8*)(sh + X_O + (XSN)*XBUF + xoff);                 \
    f32x4 rv0 = MF(w0x[0], bxc, bias0v[0]);                                    \
    f32x4 rv1 = MF(w0x[1], bxc, bias0v[1]);                                    \
    rv0 = MF(w0h[0][0], bh0[0], rv0);                                          \
    rv1 = MF(w0h[1][0], bh0[0], rv1);                                          \
    rv0 = MF(w0h[0][1], bh0[1], rv0);                                          \
    rv1 = MF(w0h[1][1], bh0[1], rv1);                                          \
    f32x4 qv0 = MF(w1i[0][0], bh0[0], bias1v[0]);                              \
    f32x4 qv1 = MF(w1i[1][0], bh0[0], bias1v[1]);                              \
    qv0 = MF(w1h[0][0], bh1[0], qv0);                                          \
    qv1 = MF(w1h[1][0], bh1[0], qv1);                                          \
    qv0 = MF(w1i[0][1], bh0[1], qv0);                                          \
    qv1 = MF(w1i[1][1], bh0[1], qv1);                                          \
    qv0 = MF(w1h[0][1], bh1[1], qv0);                                          \
    qv1 = MF(w1h[1][1], bh1[1], qv1);                                          \
    f32x2 H0 = cell2p(rv0, rv1, C0);                                           \
    *(unsigned*)(sh + H0_O + ((P) ^ 1) * HBUF + wo32) = pack2h(H0[0], H0[1]);  \
    f32x2 H1 = cell2p(qv0, qv1, C1);                                           \
    *(unsigned*)(sh + H1_O + ((P) ^ 1) * HBUF + wo32) = pack2h(H1[0], H1[1]);  \
    bxc = bxn;                                                                 \
  } while (0)

// wave 7: ds-write XR (holds x[t+3]) into literal SLOT=(t+3)&3, load x[t+5].
#define STEPX(T, SLOT, XR)                                                     \
  do {                                                                         \
    half4v h4;                                                                 \
    _Pragma("unroll") for (int i = 0; i < 4; ++i)                              \
        h4[i] = (_Float16)((const float*)&(XR))[i];                            \
    *(half4v*)(sh + X_O + (SLOT)*XBUF + sbb * 80 + q * 8) = h4;                \
    int tl = (T) + 5;                                                          \
    if (tl > TSTEPS - 1) tl = TSTEPS - 1;                                      \
    (XR) = *(const float4*)(xrow + (size_t)tl * DIN);                          \
  } while (0)

  for (int s = 0; s < TSTEPS; s += 4) {
    // phase s   (P=0): uses x[s+1] (bxc), prefetch slot 2 = x[s+2]
    if (comp) { STEPCOMP(0, 2); } else if (wv == 7) { STEPX(s, 3, xrA); }
    BAR();
    // phase s+1 (P=1): uses x[s+2], prefetch slot 3 = x[s+3]
    if (comp) { STEPCOMP(1, 3); } else if (wv == 7) { STEPX(s + 1, 0, xrB); }
    BAR();
    // phase s+2 (P=0): uses x[s+3], prefetch slot 0 = x[s+4]
    if (comp) { STEPCOMP(0, 0); } else if (wv == 7) { STEPX(s + 2, 1, xrA); }
    BAR();
    // phase s+3 (P=1): uses x[s+4], prefetch slot 1 = x[s+5]
    if (comp) { STEPCOMP(1, 1); } else if (wv == 7) { STEPX(s + 3, 2, xrB); }
    BAR();
  }

  // ---- FC epilogue: h1[511] in buf 0; read through pi-permutation ----
  if (tid < BPB) {
    float acc = bfc[0];
#pragma unroll 10
    for (int u = 0; u < HID; ++u) {
      const int pp = (u & ~7) + 2 * (u & 3) + ((u >> 2) & 1);
      float h = (float)(*(const _Float16*)(sh + H1_O + tid * 144 + pp * 2));
      acc = fmaf(Wfc[u], h, acc);
    }
    out[bbase + tid] = acc;
  }
}

extern "C" void kernel_launch(void* const* d_in, const int* in_sizes, int n_in,
                              void* d_out, int out_size, void* d_ws, size_t ws_size,
                              hipStream_t stream) {
  (void)in_sizes; (void)n_in; (void)d_ws; (void)ws_size; (void)out_size;
  lstm2_v10<<<dim3(4096 / BPB), dim3(512), 0, stream>>>(
      (const float*)d_in[0], (const float*)d_in[1], (const float*)d_in[2],
      (const float*)d_in[3], (const float*)d_in[4], (const float*)d_in[5],
      (const float*)d_in[6], (const float*)d_in[7], (const float*)d_in[8],
      (const float*)d_in[9], (const float*)d_in[10], (float*)d_out);
}